// Round 1
// baseline (613.263 us; speedup 1.0000x reference)
//
#include <hip/hip_runtime.h>

#define NB  4
#define CCH 256
#define NN  4096
#define KD  32
#define OD  256

typedef __attribute__((ext_vector_type(8))) __bf16 bf16x8;
typedef __attribute__((ext_vector_type(4))) float  floatx4;

__device__ __forceinline__ unsigned short f2bf(float f) {
    union { float f; unsigned u; } v; v.f = f;
    unsigned r = v.u + 0x7FFFu + ((v.u >> 16) & 1u);
    return (unsigned short)(r >> 16);
}

// ---------------------------------------------------------------------------
// Projection kernel:
//   chunk 0: Qb[b][n][k]  = (Wq x + bq)   (bf16, (N,K) layout = MFMA A-frag)
//   chunk 1: Ktb[b][n][k] = (Wk x + bk)   (bf16, (N,K) layout = MFMA B-frag)
//   chunks 2..9: Vb[b][o][n] = (Wv x + bv) (bf16, 32 o-rows per chunk)
// grid (10, 16, 4) = (chunk, ntile, batch), 256 threads; thread owns column n.
// W reads are wave-uniform -> s_load; x reads coalesced across threads.
// ---------------------------------------------------------------------------
__global__ __launch_bounds__(256) void proj_kernel(
    const float* __restrict__ x,
    const float* __restrict__ Wq, const float* __restrict__ bq,
    const float* __restrict__ Wk, const float* __restrict__ bk,
    const float* __restrict__ Wv, const float* __restrict__ bv,
    unsigned short* __restrict__ Qb, unsigned short* __restrict__ Ktb,
    unsigned short* __restrict__ Vb)
{
    const int chunk = blockIdx.x;
    const int ntile = blockIdx.y;
    const int b     = blockIdx.z;
    const int tid   = threadIdx.x;
    const int n     = ntile * 256 + tid;

    const float* Wsrc;
    const float* bsrc;
    if (chunk == 0)      { Wsrc = Wq; bsrc = bq; }
    else if (chunk == 1) { Wsrc = Wk; bsrc = bk; }
    else                 { Wsrc = Wv + (size_t)(chunk - 2) * 32 * CCH;
                           bsrc = bv + (chunk - 2) * 32; }

    float acc[32];
    #pragma unroll
    for (int j = 0; j < 32; ++j) acc[j] = bsrc[j];

    const float* xp = x + (size_t)b * CCH * NN + n;
    for (int c = 0; c < CCH; c += 4) {
        float xv0 = xp[(size_t)(c + 0) * NN];
        float xv1 = xp[(size_t)(c + 1) * NN];
        float xv2 = xp[(size_t)(c + 2) * NN];
        float xv3 = xp[(size_t)(c + 3) * NN];
        #pragma unroll
        for (int j = 0; j < 32; ++j) {
            floatx4 w = *(const floatx4*)(Wsrc + j * CCH + c);
            acc[j] += w[0] * xv0;
            acc[j] += w[1] * xv1;
            acc[j] += w[2] * xv2;
            acc[j] += w[3] * xv3;
        }
    }

    if (chunk < 2) {
        unsigned short* dst = (chunk ? Ktb : Qb) + (size_t)(b * NN + n) * KD;
        __align__(16) unsigned short tmp[32];
        #pragma unroll
        for (int j = 0; j < 32; ++j) tmp[j] = f2bf(acc[j]);
        #pragma unroll
        for (int i = 0; i < 4; ++i)
            ((bf16x8*)dst)[i] = ((const bf16x8*)tmp)[i];
    } else {
        const int o0 = (chunk - 2) * 32;
        #pragma unroll
        for (int j = 0; j < 32; ++j)
            Vb[(size_t)(b * OD + o0 + j) * NN + n] = f2bf(acc[j]);
    }
}

// ---------------------------------------------------------------------------
// Fused attention: 256 blocks (b, 64-row m-tile), 4 waves, wave owns 16 rows.
// pass1 row-max, pass2 row-sumexp, pass3 emit attention + PV via LDS
// P transpose (C-layout -> A-layout) and LDS-staged V tiles.
// Epilogue: LDS transpose of O so out[b][o][m] stores are dwordx4-coalesced.
// ---------------------------------------------------------------------------
__global__ __launch_bounds__(256) void attn_kernel(
    const float* __restrict__ x, const float* __restrict__ gammap,
    const unsigned short* __restrict__ Qb,
    const unsigned short* __restrict__ Ktb,
    const unsigned short* __restrict__ Vb,
    float* __restrict__ out, float* __restrict__ attn)
{
    __shared__ __align__(16) unsigned char smem[41984];
    unsigned short* Vlds = (unsigned short*)smem;                        // [256][72] bf16 (pad 8 kills b128 bank conflicts)
    const int tid  = threadIdx.x;
    const int wave = tid >> 6;
    const int lane = tid & 63;
    const int quad = lane >> 4;
    const int li   = lane & 15;
    unsigned short* Plds = (unsigned short*)(smem + 36864) + wave * 640; // [16][40] bf16 per wave

    const int b  = blockIdx.x >> 6;
    const int mw = (blockIdx.x & 63) * 64 + wave * 16;  // this wave's 16 query rows

    const floatx4 zero = {0.f, 0.f, 0.f, 0.f};

    // A-frag (Q rows), loaded once: A[m=li][k=quad*8+j] -> 16B contiguous
    const bf16x8 aQ = *(const bf16x8*)(Qb + (size_t)(b * NN + mw + li) * KD + quad * 8);
    const unsigned short* ktbase = Ktb + (size_t)b * NN * KD + quad * 8;

    // ---- pass 1: row max ----
    float mrow[4] = {-1e30f, -1e30f, -1e30f, -1e30f};
    #pragma unroll 4
    for (int nt = 0; nt < NN / 16; ++nt) {
        bf16x8 bK = *(const bf16x8*)(ktbase + (size_t)(nt * 16 + li) * KD);
        floatx4 s = __builtin_amdgcn_mfma_f32_16x16x32_bf16(aQ, bK, zero, 0, 0, 0);
        #pragma unroll
        for (int r = 0; r < 4; ++r) mrow[r] = fmaxf(mrow[r], s[r]);
    }
    #pragma unroll
    for (int r = 0; r < 4; ++r) {
        #pragma unroll
        for (int xm = 1; xm < 16; xm <<= 1)
            mrow[r] = fmaxf(mrow[r], __shfl_xor(mrow[r], xm));
    }

    // ---- pass 2: row sum of exp(s - max) ----
    float lrow[4] = {0.f, 0.f, 0.f, 0.f};
    #pragma unroll 4
    for (int nt = 0; nt < NN / 16; ++nt) {
        bf16x8 bK = *(const bf16x8*)(ktbase + (size_t)(nt * 16 + li) * KD);
        floatx4 s = __builtin_amdgcn_mfma_f32_16x16x32_bf16(aQ, bK, zero, 0, 0, 0);
        #pragma unroll
        for (int r = 0; r < 4; ++r) lrow[r] += __expf(s[r] - mrow[r]);
    }
    float linv[4];
    #pragma unroll
    for (int r = 0; r < 4; ++r) {
        #pragma unroll
        for (int xm = 1; xm < 16; xm <<= 1)
            lrow[r] += __shfl_xor(lrow[r], xm);
        linv[r] = 1.0f / lrow[r];
    }

    // ---- pass 3: emit normalized attention + accumulate PV ----
    floatx4 oacc[16];
    #pragma unroll
    for (int ot = 0; ot < 16; ++ot) oacc[ot] = zero;

    const unsigned short* vbase = Vb + (size_t)b * OD * NN;

    for (int ch = 0; ch < 64; ++ch) {
        const int n0 = ch * 64;
        __syncthreads();
        // stage V[0..255][n0..n0+63] into LDS (32KB), shared by all 4 waves
        #pragma unroll
        for (int i = 0; i < 8; ++i) {
            int linear = i * 256 + tid;          // 0..2047 x 16B = 32KB
            int o = linear >> 3, part = linear & 7;
            *(bf16x8*)(Vlds + o * 72 + part * 8) =
                *(const bf16x8*)(vbase + (size_t)o * NN + n0 + part * 8);
        }
        __syncthreads();

        #pragma unroll
        for (int sub = 0; sub < 2; ++sub) {
            const int nn0 = n0 + sub * 32;
            bf16x8 bK0 = *(const bf16x8*)(ktbase + (size_t)(nn0 + li) * KD);
            bf16x8 bK1 = *(const bf16x8*)(ktbase + (size_t)(nn0 + 16 + li) * KD);
            floatx4 s0 = __builtin_amdgcn_mfma_f32_16x16x32_bf16(aQ, bK0, zero, 0, 0, 0);
            floatx4 s1 = __builtin_amdgcn_mfma_f32_16x16x32_bf16(aQ, bK1, zero, 0, 0, 0);
            #pragma unroll
            for (int r = 0; r < 4; ++r) {
                float p0 = __expf(s0[r] - mrow[r]) * linv[r];
                float p1 = __expf(s1[r] - mrow[r]) * linv[r];
                const int row = quad * 4 + r;
                float* ap = attn + (size_t)(b * NN + mw + row) * NN + nn0 + li;
                ap[0]  = p0;
                ap[16] = p1;
                Plds[row * 40 + li]      = f2bf(p0);   // C-layout -> row-major bf16
                Plds[row * 40 + 16 + li] = f2bf(p1);
            }
            // A-frag of P: A[m=li][k=quad*8+j] (wave-internal LDS round-trip)
            bf16x8 aP = *(const bf16x8*)(Plds + li * 40 + quad * 8);
            #pragma unroll
            for (int ot = 0; ot < 16; ++ot) {
                bf16x8 bV = *(const bf16x8*)(Vlds + (ot * 16 + li) * 72 + sub * 32 + quad * 8);
                oacc[ot] = __builtin_amdgcn_mfma_f32_16x16x32_bf16(aP, bV, oacc[ot], 0, 0, 0);
            }
        }
    }

    // ---- epilogue: out[b][o][m] = gamma * O[m][o] + x[b][o][m] ----
    __syncthreads();   // Olds overlaps Vlds/Plds
    const float g = gammap[0];
    float* Olds = (float*)(void*)smem + wave * 2560;   // [128][20] fp32 per wave, 2 halves
    #pragma unroll
    for (int h = 0; h < 2; ++h) {
        #pragma unroll
        for (int t = 0; t < 8; ++t) {
            const int ot = h * 8 + t;
            #pragma unroll
            for (int r = 0; r < 4; ++r)
                Olds[(t * 16 + li) * 20 + quad * 4 + r] = oacc[ot][r];
        }
        #pragma unroll
        for (int it = 0; it < 8; ++it) {
            int linear = it * 64 + lane;
            int ol = linear >> 2;                 // 0..127 local o
            int mp = (lane & 3) * 4;              // m sub-offset
            floatx4 ov = *(const floatx4*)(Olds + ol * 20 + mp);
            int o = h * 128 + ol;
            size_t gidx = (size_t)(b * OD + o) * NN + mw + mp;
            floatx4 xv = *(const floatx4*)(x + gidx);
            floatx4 res;
            res[0] = g * ov[0] + xv[0];
            res[1] = g * ov[1] + xv[1];
            res[2] = g * ov[2] + xv[2];
            res[3] = g * ov[3] + xv[3];
            *(floatx4*)(out + gidx) = res;
        }
    }
}

extern "C" void kernel_launch(void* const* d_in, const int* in_sizes, int n_in,
                              void* d_out, int out_size, void* d_ws, size_t ws_size,
                              hipStream_t stream) {
    const float* x     = (const float*)d_in[0];
    const float* Wq    = (const float*)d_in[1];
    const float* bq    = (const float*)d_in[2];
    const float* Wk    = (const float*)d_in[3];
    const float* bk    = (const float*)d_in[4];
    const float* Wv    = (const float*)d_in[5];
    const float* bv    = (const float*)d_in[6];
    const float* gamma = (const float*)d_in[7];

    float* out  = (float*)d_out;
    float* attn = out + (size_t)NB * OD * NN;          // outputs concatenated: out then attention

    unsigned short* Qb  = (unsigned short*)d_ws;       // B*N*32 bf16 = 1 MB
    unsigned short* Ktb = Qb  + (size_t)NB * NN * KD;  // 1 MB
    unsigned short* Vb  = Ktb + (size_t)NB * NN * KD;  // B*O*N bf16 = 8 MB

    proj_kernel<<<dim3(10, 16, 4), 256, 0, stream>>>(x, Wq, bq, Wk, bk, Wv, bv, Qb, Ktb, Vb);
    attn_kernel<<<dim3(256), 256, 0, stream>>>(x, gamma, Qb, Ktb, Vb, out, attn);
}